// Round 9
// baseline (1042.805 us; speedup 1.0000x reference)
//
#include <hip/hip_runtime.h>
#include <stdint.h>

// ---------- types ----------
typedef __attribute__((ext_vector_type(8))) _Float16 half8;
typedef __attribute__((ext_vector_type(2))) __fp16   fp16x2;
typedef __attribute__((ext_vector_type(4))) float    f32x4;
typedef __attribute__((ext_vector_type(4))) unsigned short us4;

__device__ __forceinline__ unsigned short f2h(float f) {
  union { _Float16 h; unsigned short u; } cv; cv.h = (_Float16)f; return cv.u;
}

// async global->LDS, 16B per lane. lds base wave-uniform; HW adds lane*16.
__device__ __forceinline__ void async_copy16(void* lds, const void* g) {
  __builtin_amdgcn_global_load_lds(
      (__attribute__((address_space(1))) void*)(void*)g,
      (__attribute__((address_space(3))) void*)lds, 16, 0, 0);
}

union U64 { fp16x2 h2[2]; us4 u4; };

// ---------- fused f32 -> f16 conversion (7 regions, 1 launch) ----------
__global__ __launch_bounds__(256) void cvt_all(
    const float* __restrict__ q, const float* __restrict__ k, const float* __restrict__ v,
    const float* __restrict__ wq, const float* __restrict__ wk,
    const float* __restrict__ wv, const float* __restrict__ wo,
    unsigned short* __restrict__ oq, unsigned short* __restrict__ ok,
    unsigned short* __restrict__ ov,
    unsigned short* __restrict__ owq, unsigned short* __restrict__ owk,
    unsigned short* __restrict__ owv, unsigned short* __restrict__ owo) {
  int b = blockIdx.x;
  const float* in; unsigned short* out;
  if      (b < 8192)  { in = q;  out = oq;             }
  else if (b < 16384) { in = k;  out = ok;  b -= 8192; }
  else if (b < 24576) { in = v;  out = ov;  b -= 16384; }
  else if (b < 25600) { in = wq; out = owq; b -= 24576; }
  else if (b < 26624) { in = wk; out = owk; b -= 25600; }
  else if (b < 27648) { in = wv; out = owv; b -= 26624; }
  else                { in = wo; out = owo; b -= 27648; }
  const int i = (b * 256 + threadIdx.x) * 4;
  const float4 x = *(const float4*)(in + i);
  us4 o; o.x = f2h(x.x); o.y = f2h(x.y); o.z = f2h(x.z); o.w = f2h(x.w);
  *(us4*)(out + i) = o;
}

// ---------- 128x128 tile GEMM core: C = A(MxK) * W(NxK)^T, K=1024, BK=32 ----------
__device__ __forceinline__ void gemm128_core(const unsigned short* __restrict__ A,
                                             const unsigned short* __restrict__ Bw,
                                             int m0, int n0,
                                             unsigned short* As, unsigned short* Bs,
                                             f32x4 acc[4][4]) {
  const int tid  = threadIdx.x;
  const int w    = tid >> 6;
  const int l15  = tid & 15;
  const int quad = (tid >> 4) & 3;
  const int w0 = w & 1, w1 = w >> 1;
  const f32x4 zero4 = {0.f, 0.f, 0.f, 0.f};
#pragma unroll
  for (int mt = 0; mt < 4; ++mt)
#pragma unroll
    for (int nt = 0; nt < 4; ++nt) acc[mt][nt] = zero4;

  int srcR[2], srcC[2];
#pragma unroll
  for (int c = 0; c < 2; ++c) {
    const int idx = c * 256 + tid;
    srcR[c] = idx >> 2;
    srcC[c] = (idx & 3) ^ (srcR[c] & 3) ^ ((srcR[c] >> 2) & 3);
  }
  const int cs = quad ^ (l15 & 3) ^ (l15 >> 2);

  for (int k0 = 0; k0 < 1024; k0 += 32) {
    __syncthreads();
#pragma unroll
    for (int c = 0; c < 2; ++c) {
      async_copy16((char*)As + c * 4096 + w * 1024,
                   A  + (m0 + srcR[c]) * 1024 + k0 + srcC[c] * 8);
      async_copy16((char*)Bs + c * 4096 + w * 1024,
                   Bw + (n0 + srcR[c]) * 1024 + k0 + srcC[c] * 8);
    }
    __syncthreads();
    half8 af[4], bf[4];
#pragma unroll
    for (int mt = 0; mt < 4; ++mt)
      af[mt] = *(const half8*)(As + (w1 * 64 + mt * 16 + l15) * 32 + cs * 8);
#pragma unroll
    for (int nt = 0; nt < 4; ++nt)
      bf[nt] = *(const half8*)(Bs + (w0 * 64 + nt * 16 + l15) * 32 + cs * 8);
#pragma unroll
    for (int mt = 0; mt < 4; ++mt)
#pragma unroll
      for (int nt = 0; nt < 4; ++nt)
        acc[mt][nt] = __builtin_amdgcn_mfma_f32_16x16x32_f16(af[mt], bf[nt], acc[mt][nt], 0, 0, 0);
  }
}

// ---------- QKV projection; z selects Q/K/V. Q is pre-scaled by 0.125*log2(e). ----------
__global__ __launch_bounds__(256) void gemm_qkv(
    const unsigned short* __restrict__ Xq, const unsigned short* __restrict__ Xk,
    const unsigned short* __restrict__ Xv,
    const unsigned short* __restrict__ Wq, const unsigned short* __restrict__ Wk,
    const unsigned short* __restrict__ Wv,
    const float* __restrict__ bq, const float* __restrict__ bk, const float* __restrict__ bv,
    unsigned short* __restrict__ Qo, unsigned short* __restrict__ Ko,
    unsigned short* __restrict__ Vo) {
  __shared__ __align__(16) unsigned short As[128 * 32];
  __shared__ __align__(16) unsigned short Bs[128 * 32];
  const int z = blockIdx.z;
  const unsigned short* A = (z == 0) ? Xq : (z == 1) ? Xk : Xv;
  const unsigned short* W = (z == 0) ? Wq : (z == 1) ? Wk : Wv;
  const float* bias = (z == 0) ? bq : (z == 1) ? bk : bv;
  const int m0 = blockIdx.x * 128, n0 = blockIdx.y * 128;
  f32x4 acc[4][4];
  gemm128_core(A, W, m0, n0, As, Bs, acc);

  const int tid = threadIdx.x;
  const int w = tid >> 6, l15 = tid & 15, quad = (tid >> 4) & 3;
  const int w0 = w & 1, w1 = w >> 1;
  const float qscale = (z == 0) ? 0.18033688011112042f : 1.0f;  // 0.125*log2(e)
#pragma unroll
  for (int mt = 0; mt < 4; ++mt) {
    const int mbase = m0 + w1 * 64 + mt * 16 + quad * 4;  // global row = b*2048+s
    const int bb = mbase >> 11, s = mbase & 2047;
#pragma unroll
    for (int nt = 0; nt < 4; ++nt) {
      const int col = n0 + w0 * 64 + nt * 16 + l15;
      const float badd = bias[col];
      const int h = col >> 6, d = col & 63;
      if (z < 2) {
        unsigned short* dst = (z == 0) ? Qo : Ko;
#pragma unroll
        for (int r = 0; r < 4; ++r)
          dst[((bb * 16 + h) * 2048 + (s + r)) * 64 + d] = f2h((acc[mt][nt][r] + badd) * qscale);
      } else {
        us4 pk;
#pragma unroll
        for (int r = 0; r < 4; ++r) pk[r] = f2h(acc[mt][nt][r] + badd);
        *(us4*)(Vo + ((bb * 16 + h) * 64 + d) * 2048 + s) = pk;
      }
    }
  }
}

// ---------- flash attention: 16-wave blocks, key-split, in-register P ----------
// Cross-round isolation (r4/6/7/8 vs r5): with 512-thr blocks the HW co-resides
// only ~2 workgroups/CU (~17 waves, Occupancy ~37%) regardless of LDS budget;
// 1024-thr blocks reached ~32 waves (68%). So: port the lean round-7 kernel
// (in-register P via permlane swaps -> 0 bank conflicts, 8 b128/wave-kt,
// key-split additive partials) into 1024-thr blocks:
//   16 waves = 8 row-groups (wr=w&7, 32 rows each) x 2 key-halves (h=w>>3),
//   256 Q rows/block, grid (64 bh, 8 qt) = 512 blocks = exactly 2/CU = 32 waves.
// __launch_bounds__(1024, 8): 64-VGPR cap; round 7 measured 56 live -> fits.
// Tripwire: WRITE_SIZE >> 16MB means spill -> revert.
// K/V staged by thread role (tid<512 K, else V), double-buffered, one
// __syncthreads per tile (round 8 proved counted-vmcnt == drain here).
// Epilogue: h==1 waves publish acc/lsum to a 69,632B LDS arena (reuses staging
// space; sized 64 slots x 64 lanes x f32x4 + 16x64 lsum), h==0 reduce + write.
__global__ __launch_bounds__(1024, 8) void attn_kernel(const unsigned short* __restrict__ Q,
                                                       const unsigned short* __restrict__ K,
                                                       const unsigned short* __restrict__ Vt,
                                                       unsigned short* __restrict__ O) {
  __shared__ __align__(16) unsigned short SMEM[34816];  // 69,632B (2 blocks/CU = 139KB)
  unsigned short* Ks = SMEM;            // 2 bufs x 4096 halves (8,192B each)
  unsigned short* Vs = SMEM + 8192;     // 2 bufs x 4096 halves, [d][key]
  const int bh = blockIdx.x, qt = blockIdx.y;
  const int tid = threadIdx.x;
  const int w = tid >> 6, l15 = tid & 15, quad = (tid >> 4) & 3;
  const int lane = tid & 63;
  const int wr = w & 7;       // row group: rows wr*32 .. wr*32+31
  const int h  = w >> 3;      // key half: keys h*32 .. h*32+31 of every tile
  const int cq0 = quad ^ (l15 & 7), cq1 = (4 + quad) ^ (l15 & 7);

  // staging roles: waves 0-7 stage K, waves 8-15 stage V (512 lanes x 16B = tile).
  const int t9 = tid & 511;
  const int srcR = t9 >> 3;
  const int srcC = (t9 & 7) ^ (srcR & 7);
  const bool doK = (tid < 512);
  const int w8 = w & 7;

  const unsigned short* Kg0 = K + bh * 2048 * 64;
  const unsigned short* Vg0 = Vt + bh * 131072;

  auto stage_kv = [&](int t, int buf) {
    if (doK)
      async_copy16((char*)Ks + buf * 8192 + w8 * 1024, Kg0 + t * 4096 + srcR * 64 + srcC * 8);
    else
      async_copy16((char*)Vs + buf * 8192 + w8 * 1024, Vg0 + t * 64 + srcR * 2048 + srcC * 8);
  };

  // Q B-frags direct from global (both key-half groups need the same rows).
  stage_kv(0, 0);
  const unsigned short* Qg = Q + (bh * 2048 + qt * 256) * 64;
  half8 qf[2][2];
#pragma unroll
  for (int s = 0; s < 2; ++s) {
    const int row = wr * 32 + s * 16 + l15;
    qf[s][0] = *(const half8*)(Qg + row * 64 + quad * 8);
    qf[s][1] = *(const half8*)(Qg + row * 64 + 32 + quad * 8);
  }
  __syncthreads();  // drain K/V tile0

  const f32x4 zero4 = {0.f, 0.f, 0.f, 0.f};
  f32x4 acc[2][4];   // O^T partial (this key half): rows d=dt*16+quad*4+r, col=l15
  f32x4 lsum[2];
#pragma unroll
  for (int s = 0; s < 2; ++s) {
    lsum[s] = zero4;
#pragma unroll
    for (int dt = 0; dt < 4; ++dt) acc[s][dt] = zero4;
  }
  half8 ones;
#pragma unroll
  for (int i = 0; i < 8; ++i) ones[i] = (_Float16)1.0f;

  for (int kt = 0; kt < 32; ++kt) {
    if (kt < 31) stage_kv(kt + 1, (kt + 1) & 1);  // issue next tile; drains at barrier below
    const unsigned short* Kc = Ks + (kt & 1) * 4096;
    const unsigned short* Vc = Vs + (kt & 1) * 4096;

    // S^T for this wave's 32-key half; keep both 16-key batches in regs
    f32x4 z[2][2];  // [strip s][nt2]
#pragma unroll
    for (int nt2 = 0; nt2 < 2; ++nt2) {
      const int rk = h * 32 + nt2 * 16 + l15;
      half8 ak0 = *(const half8*)(Kc + rk * 64 + cq0 * 8);
      half8 ak1 = *(const half8*)(Kc + rk * 64 + cq1 * 8);
#pragma unroll
      for (int s = 0; s < 2; ++s) {
        f32x4 t = zero4;
        t = __builtin_amdgcn_mfma_f32_16x16x32_f16(ak0, qf[s][0], t, 0, 0, 0);
        t = __builtin_amdgcn_mfma_f32_16x16x32_f16(ak1, qf[s][1], t, 0, 0, 0);
        z[s][nt2] = t;
      }
    }

    // exp2 -> f16 pairs -> in-register P reshuffle -> PV B-frags
    half8 bp[2];
#pragma unroll
    for (int s = 0; s < 2; ++s) {
      union { fp16x2 h2; unsigned int u; } c;
      unsigned int a01, a23, b01, b23;
      c.h2 = __builtin_amdgcn_cvt_pkrtz(__builtin_exp2f(z[s][0][0]), __builtin_exp2f(z[s][0][1])); a01 = c.u;
      c.h2 = __builtin_amdgcn_cvt_pkrtz(__builtin_exp2f(z[s][0][2]), __builtin_exp2f(z[s][0][3])); a23 = c.u;
      c.h2 = __builtin_amdgcn_cvt_pkrtz(__builtin_exp2f(z[s][1][0]), __builtin_exp2f(z[s][1][1])); b01 = c.u;
      c.h2 = __builtin_amdgcn_cvt_pkrtz(__builtin_exp2f(z[s][1][2]), __builtin_exp2f(z[s][1][3])); b23 = c.u;
      asm("v_permlane32_swap_b32 %0, %1" : "+v"(a01), "+v"(b01));
      asm("v_permlane16_swap_b32 %0, %1" : "+v"(a01), "+v"(b01));
      asm("v_permlane32_swap_b32 %0, %1" : "+v"(a23), "+v"(b23));
      asm("v_permlane16_swap_b32 %0, %1" : "+v"(a23), "+v"(b23));
      union { unsigned int u[4]; half8 hh; } bpv;
      bpv.u[0] = a01;  // keys d*8 + {0,1}
      bpv.u[1] = a23;  // keys d*8 + {2,3}
      bpv.u[2] = b01;  // keys d*8 + {4,5}
      bpv.u[3] = b23;  // keys d*8 + {6,7}
      bp[s] = bpv.hh;
      lsum[s] = __builtin_amdgcn_mfma_f32_16x16x32_f16(ones, bp[s], lsum[s], 0, 0, 0);
    }

    // PV over the 32-key half: O^T += V^T * P^T
    const int ch = h ? cq1 : cq0;
#pragma unroll
    for (int dt = 0; dt < 4; ++dt) {
      half8 av = *(const half8*)(Vc + (dt * 16 + l15) * 64 + ch * 8);
#pragma unroll
      for (int s = 0; s < 2; ++s)
        acc[s][dt] = __builtin_amdgcn_mfma_f32_16x16x32_f16(av, bp[s], acc[s][dt], 0, 0, 0);
    }
    __syncthreads();  // drains next-tile loads (vmcnt 0) + protects K/V buffers
  }

  // merge the two key-half partials: h==1 waves publish, h==0 waves reduce+write.
  float* Red  = (float*)SMEM;     // 64 slots x 64 lanes x f32x4 = 65,536B
  float* RedL = Red + 16384;      // 16 x 64 lsum scalars = 4,096B
  if (h == 1) {
#pragma unroll
    for (int s = 0; s < 2; ++s) {
#pragma unroll
      for (int dt = 0; dt < 4; ++dt)
        *(f32x4*)(Red + (((wr * 2 + s) * 4 + dt) * 64 + lane) * 4) = acc[s][dt];
      RedL[(wr * 2 + s) * 64 + lane] = lsum[s][0];
    }
  }
  __syncthreads();
  if (h == 0) {
    const int b = bh >> 4, hd = bh & 15;
#pragma unroll
    for (int s = 0; s < 2; ++s) {
      const float ls = lsum[s][0] + RedL[(wr * 2 + s) * 64 + lane];
      const float rv = 1.0f / ls;
      const int sg = qt * 256 + wr * 32 + s * 16 + l15;
      unsigned short* Orow = O + (b * 2048 + sg) * 1024 + hd * 64;
#pragma unroll
      for (int dt = 0; dt < 4; ++dt) {
        const f32x4 p = *(const f32x4*)(Red + (((wr * 2 + s) * 4 + dt) * 64 + lane) * 4);
        U64 u;
        u.h2[0] = __builtin_amdgcn_cvt_pkrtz((acc[s][dt][0] + p[0]) * rv, (acc[s][dt][1] + p[1]) * rv);
        u.h2[1] = __builtin_amdgcn_cvt_pkrtz((acc[s][dt][2] + p[2]) * rv, (acc[s][dt][3] + p[3]) * rv);
        *(us4*)(Orow + dt * 16 + quad * 4) = u.u4;
      }
    }
  }
}

// ---------- output projection -> f32 ----------
__global__ __launch_bounds__(256) void gemm_out(const unsigned short* __restrict__ A,
                                                const unsigned short* __restrict__ W,
                                                const float* __restrict__ bias,
                                                float* __restrict__ out) {
  __shared__ __align__(16) unsigned short As[128 * 32];
  __shared__ __align__(16) unsigned short Bs[128 * 32];
  const int m0 = blockIdx.x * 128, n0 = blockIdx.y * 128;
  f32x4 acc[4][4];
  gemm128_core(A, W, m0, n0, As, Bs, acc);
  const int tid = threadIdx.x;
  const int w = tid >> 6, l15 = tid & 15, quad = (tid >> 4) & 3;
  const int w0 = w & 1, w1 = w >> 1;
#pragma unroll
  for (int mt = 0; mt < 4; ++mt) {
    const int mbase = m0 + w1 * 64 + mt * 16 + quad * 4;
#pragma unroll
    for (int nt = 0; nt < 4; ++nt) {
      const int col = n0 + w0 * 64 + nt * 16 + l15;
      const float badd = bias[col];
#pragma unroll
      for (int r = 0; r < 4; ++r)
        out[(mbase + r) * 1024 + col] = acc[mt][nt][r] + badd;
    }
  }
}

// ---------- launch ----------
extern "C" void kernel_launch(void* const* d_in, const int* in_sizes, int n_in,
                              void* d_out, int out_size, void* d_ws, size_t ws_size,
                              hipStream_t stream) {
  const float* query = (const float*)d_in[0];
  const float* key_  = (const float*)d_in[1];
  const float* value = (const float*)d_in[2];
  const float* Wq = (const float*)d_in[3];
  const float* bq = (const float*)d_in[4];
  const float* Wk = (const float*)d_in[5];
  const float* bk = (const float*)d_in[6];
  const float* Wv = (const float*)d_in[7];
  const float* bv = (const float*)d_in[8];
  const float* Wo = (const float*)d_in[9];
  const float* bo = (const float*)d_in[10];

  unsigned short* ws = (unsigned short*)d_ws;
  unsigned short* xq = ws;               // (B,S,D) f16 of query
  unsigned short* xk = xq + 8388608;
  unsigned short* xv = xk + 8388608;
  unsigned short* wq = xv + 8388608;
  unsigned short* wk = wq + 1048576;
  unsigned short* wv = wk + 1048576;
  unsigned short* wo = wv + 1048576;
  unsigned short* Qw = wo + 1048576;     // (B,H,S,64), pre-scaled by 0.125*log2e
  unsigned short* Kw = Qw + 8388608;     // (B,H,S,64)
  unsigned short* Vw = Kw + 8388608;     // (B,H,64,S) transposed
  unsigned short* Ow = xq;               // reuse query-f16 region for attn output

  cvt_all<<<28672, 256, 0, stream>>>(query, key_, value, Wq, Wk, Wv, Wo,
                                     xq, xk, xv, wq, wk, wv, wo);
  gemm_qkv<<<dim3(64, 8, 3), 256, 0, stream>>>(xq, xk, xv, wq, wk, wv, bq, bk, bv, Qw, Kw, Vw);
  attn_kernel<<<dim3(64, 8), 1024, 0, stream>>>(Qw, Kw, Vw, Ow);
  gemm_out<<<dim3(64, 8), 256, 0, stream>>>(Ow, wo, bo, (float*)d_out);
}

// Round 11
// 346.972 us; speedup vs baseline: 3.0054x; 3.0054x over previous
//
#include <hip/hip_runtime.h>
#include <stdint.h>

// ---------- types ----------
typedef __attribute__((ext_vector_type(8))) _Float16 half8;
typedef __attribute__((ext_vector_type(2))) __fp16   fp16x2;
typedef __attribute__((ext_vector_type(4))) float    f32x4;
typedef __attribute__((ext_vector_type(4))) unsigned short us4;

__device__ __forceinline__ unsigned short f2h(float f) {
  union { _Float16 h; unsigned short u; } cv; cv.h = (_Float16)f; return cv.u;
}

// async global->LDS, 16B per lane. lds base wave-uniform; HW adds lane*16.
__device__ __forceinline__ void async_copy16(void* lds, const void* g) {
  __builtin_amdgcn_global_load_lds(
      (__attribute__((address_space(1))) void*)(void*)g,
      (__attribute__((address_space(3))) void*)lds, 16, 0, 0);
}

union U64 { fp16x2 h2[2]; us4 u4; };

// ---------- fused f32 -> f16 conversion (7 regions, 1 launch) ----------
__global__ __launch_bounds__(256) void cvt_all(
    const float* __restrict__ q, const float* __restrict__ k, const float* __restrict__ v,
    const float* __restrict__ wq, const float* __restrict__ wk,
    const float* __restrict__ wv, const float* __restrict__ wo,
    unsigned short* __restrict__ oq, unsigned short* __restrict__ ok,
    unsigned short* __restrict__ ov,
    unsigned short* __restrict__ owq, unsigned short* __restrict__ owk,
    unsigned short* __restrict__ owv, unsigned short* __restrict__ owo) {
  int b = blockIdx.x;
  const float* in; unsigned short* out;
  if      (b < 8192)  { in = q;  out = oq;             }
  else if (b < 16384) { in = k;  out = ok;  b -= 8192; }
  else if (b < 24576) { in = v;  out = ov;  b -= 16384; }
  else if (b < 25600) { in = wq; out = owq; b -= 24576; }
  else if (b < 26624) { in = wk; out = owk; b -= 25600; }
  else if (b < 27648) { in = wv; out = owv; b -= 26624; }
  else                { in = wo; out = owo; b -= 27648; }
  const int i = (b * 256 + threadIdx.x) * 4;
  const float4 x = *(const float4*)(in + i);
  us4 o; o.x = f2h(x.x); o.y = f2h(x.y); o.z = f2h(x.z); o.w = f2h(x.w);
  *(us4*)(out + i) = o;
}

// ---------- 128x128 tile GEMM core: C = A(MxK) * W(NxK)^T, K=1024, BK=32 ----------
// Round-11: single-barrier double-buffer (attn-proven pattern, rounds 4-8).
// Old form had 2 barriers/K-step with the staging serialized between them
// (64 barriers/block, stage latency exposed). Now: stage k+1 into buf^1 BEFORE
// computing k; ONE __syncthreads per step (its implicit vmcnt(0) drains the
// next tile's loads AFTER the 16 MFMAs). Hazard: stage targets the buffer all
// waves finished reading last iteration, published by that barrier.
// LDS: As/Bs each 2 x 128x32 halves = 16KB -> 32KB total.
__device__ __forceinline__ void gemm128_core(const unsigned short* __restrict__ A,
                                             const unsigned short* __restrict__ Bw,
                                             int m0, int n0,
                                             unsigned short* As, unsigned short* Bs,
                                             f32x4 acc[4][4]) {
  const int tid  = threadIdx.x;
  const int w    = tid >> 6;
  const int l15  = tid & 15;
  const int quad = (tid >> 4) & 3;
  const int w0 = w & 1, w1 = w >> 1;
  const f32x4 zero4 = {0.f, 0.f, 0.f, 0.f};
#pragma unroll
  for (int mt = 0; mt < 4; ++mt)
#pragma unroll
    for (int nt = 0; nt < 4; ++nt) acc[mt][nt] = zero4;

  int srcR[2], srcC[2];
#pragma unroll
  for (int c = 0; c < 2; ++c) {
    const int idx = c * 256 + tid;
    srcR[c] = idx >> 2;
    srcC[c] = (idx & 3) ^ (srcR[c] & 3) ^ ((srcR[c] >> 2) & 3);
  }
  const int cs = quad ^ (l15 & 3) ^ (l15 >> 2);

  auto stage = [&](int k0, int buf) {
#pragma unroll
    for (int c = 0; c < 2; ++c) {
      async_copy16((char*)As + buf * 8192 + c * 4096 + w * 1024,
                   A  + (m0 + srcR[c]) * 1024 + k0 + srcC[c] * 8);
      async_copy16((char*)Bs + buf * 8192 + c * 4096 + w * 1024,
                   Bw + (n0 + srcR[c]) * 1024 + k0 + srcC[c] * 8);
    }
  };

  stage(0, 0);
  __syncthreads();  // drain tile 0

  int buf = 0;
  for (int k0 = 0; k0 < 1024; k0 += 32) {
    if (k0 + 32 < 1024) stage(k0 + 32, buf ^ 1);  // issue next tile now
    const unsigned short* Ab = As + buf * 4096;
    const unsigned short* Bb = Bs + buf * 4096;
    half8 af[4], bf[4];
#pragma unroll
    for (int mt = 0; mt < 4; ++mt)
      af[mt] = *(const half8*)(Ab + (w1 * 64 + mt * 16 + l15) * 32 + cs * 8);
#pragma unroll
    for (int nt = 0; nt < 4; ++nt)
      bf[nt] = *(const half8*)(Bb + (w0 * 64 + nt * 16 + l15) * 32 + cs * 8);
#pragma unroll
    for (int mt = 0; mt < 4; ++mt)
#pragma unroll
      for (int nt = 0; nt < 4; ++nt)
        acc[mt][nt] = __builtin_amdgcn_mfma_f32_16x16x32_f16(af[mt], bf[nt], acc[mt][nt], 0, 0, 0);
    __syncthreads();  // drains next tile's loads + protects buf reuse
    buf ^= 1;
  }
}

// ---------- QKV projection; z selects Q/K/V. Q is pre-scaled by 0.125*log2(e). ----------
__global__ __launch_bounds__(256) void gemm_qkv(
    const unsigned short* __restrict__ Xq, const unsigned short* __restrict__ Xk,
    const unsigned short* __restrict__ Xv,
    const unsigned short* __restrict__ Wq, const unsigned short* __restrict__ Wk,
    const unsigned short* __restrict__ Wv,
    const float* __restrict__ bq, const float* __restrict__ bk, const float* __restrict__ bv,
    unsigned short* __restrict__ Qo, unsigned short* __restrict__ Ko,
    unsigned short* __restrict__ Vo) {
  __shared__ __align__(16) unsigned short As[2 * 128 * 32];
  __shared__ __align__(16) unsigned short Bs[2 * 128 * 32];
  const int z = blockIdx.z;
  const unsigned short* A = (z == 0) ? Xq : (z == 1) ? Xk : Xv;
  const unsigned short* W = (z == 0) ? Wq : (z == 1) ? Wk : Wv;
  const float* bias = (z == 0) ? bq : (z == 1) ? bk : bv;
  const int m0 = blockIdx.x * 128, n0 = blockIdx.y * 128;
  f32x4 acc[4][4];
  gemm128_core(A, W, m0, n0, As, Bs, acc);

  const int tid = threadIdx.x;
  const int w = tid >> 6, l15 = tid & 15, quad = (tid >> 4) & 3;
  const int w0 = w & 1, w1 = w >> 1;
  const float qscale = (z == 0) ? 0.18033688011112042f : 1.0f;  // 0.125*log2(e)
#pragma unroll
  for (int mt = 0; mt < 4; ++mt) {
    const int mbase = m0 + w1 * 64 + mt * 16 + quad * 4;  // global row = b*2048+s
    const int bb = mbase >> 11, s = mbase & 2047;
#pragma unroll
    for (int nt = 0; nt < 4; ++nt) {
      const int col = n0 + w0 * 64 + nt * 16 + l15;
      const float badd = bias[col];
      const int h = col >> 6, d = col & 63;
      if (z < 2) {
        unsigned short* dst = (z == 0) ? Qo : Ko;
#pragma unroll
        for (int r = 0; r < 4; ++r)
          dst[((bb * 16 + h) * 2048 + (s + r)) * 64 + d] = f2h((acc[mt][nt][r] + badd) * qscale);
      } else {
        us4 pk;
#pragma unroll
        for (int r = 0; r < 4; ++r) pk[r] = f2h(acc[mt][nt][r] + badd);
        *(us4*)(Vo + ((bb * 16 + h) * 64 + d) * 2048 + s) = pk;
      }
    }
  }
}

// ---------- flash attention: key-split waves, in-register P, counted-vmcnt ring ----------
// Round-8 kernel verbatim (106.8us, passed twice). 512 thr = 4 row-groups x 2
// key-halves, 128 Q rows/block, grid (64 bh, 16 qt); bh-major = XCD locality.
// 3-buffer ring, prefetch depth 2, s_waitcnt vmcnt(2) + raw s_barrier per tile;
// in-register P via permlane swaps (0 bank conflicts); additive key-half
// partials merged by an end LDS reduction.
__global__ __launch_bounds__(512, 4) void attn_kernel(const unsigned short* __restrict__ Q,
                                                      const unsigned short* __restrict__ K,
                                                      const unsigned short* __restrict__ Vt,
                                                      unsigned short* __restrict__ O) {
  __shared__ __align__(16) unsigned short SMEM[24576];  // 49,152B
  unsigned short* Ks = SMEM;            // 3 bufs x 4096 halves (8,192B each)
  unsigned short* Vs = SMEM + 12288;    // 3 bufs x 4096 halves, [d][key]
  const int bh = blockIdx.x, qt = blockIdx.y;
  const int tid = threadIdx.x;
  const int w = tid >> 6, l15 = tid & 15, quad = (tid >> 4) & 3;
  const int lane = tid & 63;
  const int wr = w & 3;       // row group: rows wr*32 .. wr*32+31
  const int h  = w >> 2;      // key half: keys h*32 .. h*32+31 of every tile
  const int cq0 = quad ^ (l15 & 7), cq1 = (4 + quad) ^ (l15 & 7);

  // K/V tile staging: 512 threads x 16B x2 = both 64x64 f16 tiles per call.
  const int srcR = tid >> 3;
  const int srcC = (tid & 7) ^ (srcR & 7);

  const unsigned short* Kg0 = K + bh * 2048 * 64;
  const unsigned short* Vg0 = Vt + bh * 131072;

  auto stage_kv = [&](int t, int buf) {
    async_copy16((char*)Ks + buf * 8192 + w * 1024, Kg0 + t * 4096 + srcR * 64 + srcC * 8);
    async_copy16((char*)Vs + buf * 8192 + w * 1024, Vg0 + t * 64 + srcR * 2048 + srcC * 8);
  };

  // Q B-frags direct from global (both key-half groups need the same rows).
  const unsigned short* Qg = Q + (bh * 2048 + qt * 128) * 64;
  half8 qf[2][2];
#pragma unroll
  for (int s = 0; s < 2; ++s) {
    const int row = wr * 32 + s * 16 + l15;
    qf[s][0] = *(const half8*)(Qg + row * 64 + quad * 8);
    qf[s][1] = *(const half8*)(Qg + row * 64 + 32 + quad * 8);
  }
  stage_kv(0, 0);
  stage_kv(1, 1);

  const f32x4 zero4 = {0.f, 0.f, 0.f, 0.f};
  f32x4 acc[2][4];   // O^T partial (this key half): rows d=dt*16+quad*4+r, col=l15
  f32x4 lsum[2];
#pragma unroll
  for (int s = 0; s < 2; ++s) {
    lsum[s] = zero4;
#pragma unroll
    for (int dt = 0; dt < 4; ++dt) acc[s][dt] = zero4;
  }
  half8 ones;
#pragma unroll
  for (int i = 0; i < 8; ++i) ones[i] = (_Float16)1.0f;

  int cur = 0;  // ring position: tile kt lives in buffer cur = kt % 3
  for (int kt = 0; kt < 32; ++kt) {
    if (kt == 31) asm volatile("s_waitcnt vmcnt(0)" ::: "memory");
    else          asm volatile("s_waitcnt vmcnt(2)" ::: "memory");
    __builtin_amdgcn_s_barrier();
    __builtin_amdgcn_sched_barrier(0);
    if (kt + 2 < 32) {
      int nb = cur + 2; if (nb >= 3) nb -= 3;  // (kt+2)%3
      stage_kv(kt + 2, nb);
    }
    const unsigned short* Kc = Ks + cur * 4096;
    const unsigned short* Vc = Vs + cur * 4096;

    // S^T for this wave's 32-key half; keep both 16-key batches in regs
    f32x4 z[2][2];  // [strip s][nt2]
#pragma unroll
    for (int nt2 = 0; nt2 < 2; ++nt2) {
      const int rk = h * 32 + nt2 * 16 + l15;
      half8 ak0 = *(const half8*)(Kc + rk * 64 + cq0 * 8);
      half8 ak1 = *(const half8*)(Kc + rk * 64 + cq1 * 8);
#pragma unroll
      for (int s = 0; s < 2; ++s) {
        f32x4 t = zero4;
        t = __builtin_amdgcn_mfma_f32_16x16x32_f16(ak0, qf[s][0], t, 0, 0, 0);
        t = __builtin_amdgcn_mfma_f32_16x16x32_f16(ak1, qf[s][1], t, 0, 0, 0);
        z[s][nt2] = t;
      }
    }

    // exp2 -> f16 pairs -> in-register P reshuffle -> PV B-frags
    half8 bp[2];
#pragma unroll
    for (int s = 0; s < 2; ++s) {
      union { fp16x2 h2; unsigned int u; } c;
      unsigned int a01, a23, b01, b23;
      c.h2 = __builtin_amdgcn_cvt_pkrtz(__builtin_exp2f(z[s][0][0]), __builtin_exp2f(z[s][0][1])); a01 = c.u;
      c.h2 = __builtin_amdgcn_cvt_pkrtz(__builtin_exp2f(z[s][0][2]), __builtin_exp2f(z[s][0][3])); a23 = c.u;
      c.h2 = __builtin_amdgcn_cvt_pkrtz(__builtin_exp2f(z[s][1][0]), __builtin_exp2f(z[s][1][1])); b01 = c.u;
      c.h2 = __builtin_amdgcn_cvt_pkrtz(__builtin_exp2f(z[s][1][2]), __builtin_exp2f(z[s][1][3])); b23 = c.u;
      asm("v_permlane32_swap_b32 %0, %1" : "+v"(a01), "+v"(b01));
      asm("v_permlane16_swap_b32 %0, %1" : "+v"(a01), "+v"(b01));
      asm("v_permlane32_swap_b32 %0, %1" : "+v"(a23), "+v"(b23));
      asm("v_permlane16_swap_b32 %0, %1" : "+v"(a23), "+v"(b23));
      union { unsigned int u[4]; half8 hh; } bpv;
      bpv.u[0] = a01;  // keys d*8 + {0,1}
      bpv.u[1] = a23;  // keys d*8 + {2,3}
      bpv.u[2] = b01;  // keys d*8 + {4,5}
      bpv.u[3] = b23;  // keys d*8 + {6,7}
      bp[s] = bpv.hh;
      lsum[s] = __builtin_amdgcn_mfma_f32_16x16x32_f16(ones, bp[s], lsum[s], 0, 0, 0);
    }

    // PV over the 32-key half: O^T += V^T * P^T
    const int ch = h ? cq1 : cq0;
#pragma unroll
    for (int dt = 0; dt < 4; ++dt) {
      half8 av = *(const half8*)(Vc + (dt * 16 + l15) * 64 + ch * 8);
#pragma unroll
      for (int s = 0; s < 2; ++s)
        acc[s][dt] = __builtin_amdgcn_mfma_f32_16x16x32_f16(av, bp[s], acc[s][dt], 0, 0, 0);
    }
    cur = (cur == 2) ? 0 : cur + 1;
  }
  __syncthreads();  // all K/V reads done before arena reuse below

  // merge the two key-half partials: h==1 waves publish, h==0 waves reduce+write.
  float* Red  = (float*)SMEM;     // 32 slots x 64 lanes x f32x4 = 32,768B
  float* RedL = Red + 8192;       // 8 x 64 lsum scalars = 2,048B
  if (h == 1) {
#pragma unroll
    for (int s = 0; s < 2; ++s) {
#pragma unroll
      for (int dt = 0; dt < 4; ++dt)
        *(f32x4*)(Red + (((wr * 2 + s) * 4 + dt) * 64 + lane) * 4) = acc[s][dt];
      RedL[(wr * 2 + s) * 64 + lane] = lsum[s][0];
    }
  }
  __syncthreads();
  if (h == 0) {
    const int b = bh >> 4, hd = bh & 15;
#pragma unroll
    for (int s = 0; s < 2; ++s) {
      const float ls = lsum[s][0] + RedL[(wr * 2 + s) * 64 + lane];
      const float rv = 1.0f / ls;
      const int sg = qt * 128 + wr * 32 + s * 16 + l15;
      unsigned short* Orow = O + (b * 2048 + sg) * 1024 + hd * 64;
#pragma unroll
      for (int dt = 0; dt < 4; ++dt) {
        const f32x4 p = *(const f32x4*)(Red + (((wr * 2 + s) * 4 + dt) * 64 + lane) * 4);
        U64 u;
        u.h2[0] = __builtin_amdgcn_cvt_pkrtz((acc[s][dt][0] + p[0]) * rv, (acc[s][dt][1] + p[1]) * rv);
        u.h2[1] = __builtin_amdgcn_cvt_pkrtz((acc[s][dt][2] + p[2]) * rv, (acc[s][dt][3] + p[3]) * rv);
        *(us4*)(Orow + dt * 16 + quad * 4) = u.u4;
      }
    }
  }
}

// ---------- output projection -> f32 ----------
__global__ __launch_bounds__(256) void gemm_out(const unsigned short* __restrict__ A,
                                                const unsigned short* __restrict__ W,
                                                const float* __restrict__ bias,
                                                float* __restrict__ out) {
  __shared__ __align__(16) unsigned short As[2 * 128 * 32];
  __shared__ __align__(16) unsigned short Bs[2 * 128 * 32];
  const int m0 = blockIdx.x * 128, n0 = blockIdx.y * 128;
  f32x4 acc[4][4];
  gemm128_core(A, W, m0, n0, As, Bs, acc);
  const int tid = threadIdx.x;
  const int w = tid >> 6, l15 = tid & 15, quad = (tid >> 4) & 3;
  const int w0 = w & 1, w1 = w >> 1;
#pragma unroll
  for (int mt = 0; mt < 4; ++mt) {
    const int mbase = m0 + w1 * 64 + mt * 16 + quad * 4;
#pragma unroll
    for (int nt = 0; nt < 4; ++nt) {
      const int col = n0 + w0 * 64 + nt * 16 + l15;
      const float badd = bias[col];
#pragma unroll
      for (int r = 0; r < 4; ++r)
        out[(mbase + r) * 1024 + col] = acc[mt][nt][r] + badd;
    }
  }
}

// ---------- launch ----------
extern "C" void kernel_launch(void* const* d_in, const int* in_sizes, int n_in,
                              void* d_out, int out_size, void* d_ws, size_t ws_size,
                              hipStream_t stream) {
  const float* query = (const float*)d_in[0];
  const float* key_  = (const float*)d_in[1];
  const float* value = (const float*)d_in[2];
  const float* Wq = (const float*)d_in[3];
  const float* bq = (const float*)d_in[4];
  const float* Wk = (const float*)d_in[5];
  const float* bk = (const float*)d_in[6];
  const float* Wv = (const float*)d_in[7];
  const float* bv = (const float*)d_in[8];
  const float* Wo = (const float*)d_in[9];
  const float* bo = (const float*)d_in[10];

  unsigned short* ws = (unsigned short*)d_ws;
  unsigned short* xq = ws;               // (B,S,D) f16 of query
  unsigned short* xk = xq + 8388608;
  unsigned short* xv = xk + 8388608;
  unsigned short* wq = xv + 8388608;
  unsigned short* wk = wq + 1048576;
  unsigned short* wv = wk + 1048576;
  unsigned short* wo = wv + 1048576;
  unsigned short* Qw = wo + 1048576;     // (B,H,S,64), pre-scaled by 0.125*log2e
  unsigned short* Kw = Qw + 8388608;     // (B,H,S,64)
  unsigned short* Vw = Kw + 8388608;     // (B,H,64,S) transposed
  unsigned short* Ow = xq;               // reuse query-f16 region for attn output

  cvt_all<<<28672, 256, 0, stream>>>(query, key_, value, Wq, Wk, Wv, Wo,
                                     xq, xk, xv, wq, wk, wv, wo);
  gemm_qkv<<<dim3(64, 8, 3), 256, 0, stream>>>(xq, xk, xv, wq, wk, wv, bq, bk, bv, Qw, Kw, Vw);
  attn_kernel<<<dim3(64, 16), 512, 0, stream>>>(Qw, Kw, Vw, Ow);
  gemm_out<<<dim3(64, 8), 256, 0, stream>>>(Ow, wo, bo, (float*)d_out);
}